// Round 1
// 470.299 us; speedup vs baseline: 1.0159x; 1.0159x over previous
//
#include <hip/hip_runtime.h>
#include <math.h>

#define BB 8
#define CC 512
#define KK 19
#define HWHW 16384
#define INV_HW (1.0f/16384.0f)

typedef __attribute__((ext_vector_type(8))) short bf16x8;
typedef __attribute__((ext_vector_type(4))) short s16x4;
typedef __attribute__((ext_vector_type(4))) float f32x4;

__device__ __forceinline__ unsigned short f2bf(float f) {
    unsigned int u = __float_as_uint(f);
    u = (u + 0x7fffu + ((u >> 16) & 1u)) >> 16;
    return (unsigned short)u;
}

// pack 2 floats -> 2 bf16 (RNE, identical to f2bf) in one instruction
__device__ __forceinline__ unsigned int pk_bf16(float a, float b) {
    unsigned int r;
    asm("v_cvt_pk_bf16_f32 %0, %1, %2" : "=v"(r) : "v"(a), "v"(b));
    return r;
}

// ================= k_s1: mask = sigmoid(Wm @ x + bm), bf16 out ==============
// Pipelined: double-buffered LDS x-tile; next-cs global loads issued at top of
// each iteration (counted vmcnt, never drained); raw s_barrier + lgkmcnt(0)
// instead of __syncthreads (keeps global loads in flight across the barrier).
__global__ __launch_bounds__(256, 3) void k_s1(const float* __restrict__ x,
                                               const float* __restrict__ Wm,
                                               const float* __restrict__ bm,
                                               unsigned short* __restrict__ mask) {
    __shared__ short wm[20 * CC];
    __shared__ short xt[2][128 * 64];
    const int tid = threadIdx.x;
    const int b = blockIdx.x >> 7;
    const int p0 = (blockIdx.x & 127) << 7;
    const float* xb = x + ((size_t)b * CC) * HWHW + p0;

    for (int u = tid; u < 20 * 128; u += 256) {
        const int k = u >> 7;
        const int c4 = (u & 127) << 2;
        float4 w = {0.f, 0.f, 0.f, 0.f};
        if (k < KK) w = *(const float4*)(Wm + k * CC + c4);
        s16x4 v = { (short)f2bf(w.x), (short)f2bf(w.y), (short)f2bf(w.z), (short)f2bf(w.w) };
        *(s16x4*)&wm[(k << 9) + (((c4 >> 3) ^ (k & 7)) << 3) + (c4 & 7)] = v;
    }

    const int wv = tid >> 6, ln = tid & 63;
    const int lm = ln & 15, q = ln >> 4;
    const f32x4 zz = {0.f, 0.f, 0.f, 0.f};
    f32x4 acc[2][2];
    acc[0][0] = zz; acc[0][1] = zz; acc[1][0] = zz; acc[1][1] = zz;

    const int cg0 = tid >> 5;            // 0..7  (h=0 c-group; h=1 adds 8)
    const int pA  = (tid & 31) << 2;     // 0..124
    const float* sA = xb + (size_t)(cg0 << 2) * HWHW + pA;
    const float* sB = xb + (size_t)((cg0 + 8) << 2) * HWHW + pA;

    float4 Fa[8], Fb[8];
#pragma unroll
    for (int j = 0; j < 4; ++j) {
        Fa[j]     = *(const float4*)(sA + (size_t)j * HWHW);
        Fa[4 + j] = *(const float4*)(sB + (size_t)j * HWHW);
    }

#pragma unroll
    for (int cs = 0; cs < 8; ++cs) {
        const float4* cur = (cs & 1) ? Fb : Fa;
        float4* nxt = (cs & 1) ? Fa : Fb;
        if (cs < 7) {                               // issue next tile EARLY
            const size_t co = (size_t)((cs + 1) << 6) * HWHW;
#pragma unroll
            for (int j = 0; j < 4; ++j) {
                nxt[j]     = *(const float4*)(sA + co + (size_t)j * HWHW);
                nxt[4 + j] = *(const float4*)(sB + co + (size_t)j * HWHW);
            }
        }
        short* xts = (short*)xt[cs & 1];
#pragma unroll
        for (int h = 0; h < 2; ++h) {
            const int cg = cg0 + (h << 3);
            const float* G0 = (const float*)&cur[(h << 2) + 0];
            const float* G1 = (const float*)&cur[(h << 2) + 1];
            const float* G2 = (const float*)&cur[(h << 2) + 2];
            const float* G3 = (const float*)&cur[(h << 2) + 3];
#pragma unroll
            for (int j = 0; j < 4; ++j) {
                const int pr = pA + j;
                uint2 v = make_uint2(pk_bf16(G0[j], G1[j]), pk_bf16(G2[j], G3[j]));
                *(uint2*)&xts[(pr << 6) + (((cg >> 1) ^ (pr & 7)) << 3) + ((cg & 1) << 2)] = v;
            }
        }
        asm volatile("s_waitcnt lgkmcnt(0)" ::: "memory");
        __builtin_amdgcn_s_barrier();
        asm volatile("" ::: "memory");
#pragma unroll
        for (int ks = 0; ks < 2; ++ks) {
            const int gch = (cs << 3) + (ks << 2) + q;
            const int m1 = (lm < 3) ? (16 + lm) : 19;
            bf16x8 a0 = *(const bf16x8*)&wm[(lm << 9) + ((gch ^ (lm & 7)) << 3)];
            bf16x8 a1 = *(const bf16x8*)&wm[(m1 << 9) + ((gch ^ (m1 & 7)) << 3)];
            const int lch = (ks << 2) + q;
#pragma unroll
            for (int nt = 0; nt < 2; ++nt) {
                const int pr = (((wv << 1) + nt) << 4) + lm;
                bf16x8 bv = *(const bf16x8*)&xts[(pr << 6) + ((lch ^ (pr & 7)) << 3)];
                acc[0][nt] = __builtin_amdgcn_mfma_f32_16x16x32_bf16(a0, bv, acc[0][nt], 0, 0, 0);
                acc[1][nt] = __builtin_amdgcn_mfma_f32_16x16x32_bf16(a1, bv, acc[1][nt], 0, 0, 0);
            }
        }
    }

    unsigned short* mb = mask + ((size_t)b * KK) * HWHW + p0;
#pragma unroll
    for (int mt = 0; mt < 2; ++mt)
#pragma unroll
        for (int r = 0; r < 4; ++r) {
            const int k = (mt << 4) + (q << 2) + r;
            if (k < KK) {
                const float bias = bm[k];
#pragma unroll
                for (int nt = 0; nt < 2; ++nt) {
                    const int p = (((wv << 1) + nt) << 4) + lm;
                    const float t = acc[mt][nt][r] + bias;
                    mb[(size_t)k * HWHW + p] = f2bf(1.0f / (1.0f + __expf(-t)));
                }
            }
        }
}

// ====== k_s2: cf_part[s][b][k][c] = sum_{p in slice} mask[k][p]*x[c][p] =====
// Same pipelining: dbuf LDS, early next-kp loads, raw barrier + lgkm-only wait.
__global__ __launch_bounds__(256, 4) void k_s2(const float* __restrict__ x,
                                               const unsigned short* __restrict__ mask,
                                               float* __restrict__ cf_part) {
    __shared__ short mt_[2][20 * 64];
    __shared__ short xtl[2][64 * 64];
    const int tid = threadIdx.x;
    const int s = blockIdx.x & 15;
    const int ct = (blockIdx.x >> 4) & 7;
    const int b = blockIdx.x >> 7;
    const int wv = tid >> 6, ln = tid & 63;
    const int lm = ln & 15, q = ln >> 4;
    const float* xb = x + ((size_t)b * CC + (ct << 6)) * HWHW + (s << 10);
    const unsigned short* mbs = mask + ((size_t)b * KK) * HWHW + (s << 10);

    const int mk = tid >> 3, mch = tid & 7;   // mask-stage coords (tid<160)
    const int xc = tid >> 4;                  // 0..15 base c (r adds 16)
    const int pq = tid & 15;

    const f32x4 zz = {0.f, 0.f, 0.f, 0.f};
    f32x4 acc[2];
    acc[0] = zz; acc[1] = zz;

    float4 Xa[4], Xb[4];
    uint4 Ma = make_uint4(0u,0u,0u,0u), Mb = make_uint4(0u,0u,0u,0u);

    if (tid < 160 && mk < KK) Ma = *(const uint4*)(mbs + (size_t)mk * HWHW + (mch << 3));
#pragma unroll
    for (int r = 0; r < 4; ++r)
        Xa[r] = *(const float4*)(xb + (size_t)(xc + (r << 4)) * HWHW + (pq << 2));

#pragma unroll
    for (int kp = 0; kp < 16; ++kp) {
        const float4* curX = (kp & 1) ? Xb : Xa;
        float4* nxtX = (kp & 1) ? Xa : Xb;
        const uint4 curM = (kp & 1) ? Mb : Ma;
        uint4* nxtM = (kp & 1) ? &Ma : &Mb;
        if (kp < 15) {                            // issue next tile EARLY
            if (tid < 160 && mk < KK)
                *nxtM = *(const uint4*)(mbs + (size_t)mk * HWHW + ((kp + 1) << 6) + (mch << 3));
#pragma unroll
            for (int r = 0; r < 4; ++r)
                nxtX[r] = *(const float4*)(xb + (size_t)(xc + (r << 4)) * HWHW + ((kp + 1) << 6) + (pq << 2));
        }
        short* mts = (short*)mt_[kp & 1];
        short* xls = (short*)xtl[kp & 1];
        if (tid < 160)
            *(uint4*)&mts[(mk << 6) + ((mch ^ (mk & 7)) << 3)] = curM;
#pragma unroll
        for (int r = 0; r < 4; ++r) {
            const int c = xc + (r << 4);
            const float* G = (const float*)&curX[r];
            uint2 v = make_uint2(pk_bf16(G[0], G[1]), pk_bf16(G[2], G[3]));
            *(uint2*)&xls[(c << 6) + (((pq >> 1) ^ (c & 7)) << 3) + ((pq & 1) << 2)] = v;
        }
        asm volatile("s_waitcnt lgkmcnt(0)" ::: "memory");
        __builtin_amdgcn_s_barrier();
        asm volatile("" ::: "memory");
#pragma unroll
        for (int ks = 0; ks < 2; ++ks) {
            const int pch = (ks << 2) + q;
            const int cr = (wv << 4) + lm;
            bf16x8 bv = *(const bf16x8*)&xls[(cr << 6) + ((pch ^ (cr & 7)) << 3)];
            const int m1 = (lm < 3) ? (16 + lm) : 19;
            bf16x8 a0 = *(const bf16x8*)&mts[(lm << 6) + ((pch ^ (lm & 7)) << 3)];
            bf16x8 a1 = *(const bf16x8*)&mts[(m1 << 6) + ((pch ^ (m1 & 7)) << 3)];
            acc[0] = __builtin_amdgcn_mfma_f32_16x16x32_bf16(a0, bv, acc[0], 0, 0, 0);
            acc[1] = __builtin_amdgcn_mfma_f32_16x16x32_bf16(a1, bv, acc[1], 0, 0, 0);
        }
    }

    float* dst = cf_part + ((size_t)(s * BB + b) * KK) * CC + (ct << 6) + (wv << 4) + lm;
#pragma unroll
    for (int mt = 0; mt < 2; ++mt)
#pragma unroll
        for (int r = 0; r < 4; ++r) {
            const int k = (mt << 4) + (q << 2) + r;
            if (k < KK) dst[(size_t)k * CC] = acc[mt][r];
        }
}

// ========== k_s2r: cf = INV_HW * sum_s cf_part ==========
__global__ __launch_bounds__(256) void k_s2r(const float* __restrict__ part,
                                             float* __restrict__ cf) {
    const int i = blockIdx.x * 256 + threadIdx.x;
    if (i >= BB * KK * CC) return;
    const int b = i / (KK * CC);
    const int rem = i - b * (KK * CC);
    float sum = 0.0f;
#pragma unroll
    for (int s = 0; s < 16; ++s)
        sum += part[((size_t)(s * BB + b) * KK) * CC + rem];
    cf[i] = sum * INV_HW;
}

// ====== k_filters: fil[b,k,o] = sum_c Wf[k,o,c]*cf[b,k,c] + bf[k,o] ======
__global__ __launch_bounds__(256) void k_filters(const float* __restrict__ Wf,
                                                 const float* __restrict__ bf,
                                                 const float* __restrict__ cf,
                                                 float* __restrict__ fil) {
    const int blk = blockIdx.x;
    const int k = blk >> 7;
    const int o = ((blk & 127) << 2) + (threadIdx.x >> 6);
    const int lane = threadIdx.x & 63;
    const float* wrow = Wf + ((size_t)k * CC + o) * CC;

    float acc[BB];
#pragma unroll
    for (int b = 0; b < BB; ++b) acc[b] = 0.0f;
#pragma unroll
    for (int j = 0; j < CC / 64; ++j) {
        const int c = lane + (j << 6);
        const float wv = wrow[c];
#pragma unroll
        for (int b = 0; b < BB; ++b)
            acc[b] += wv * cf[((size_t)b * KK + k) * CC + c];
    }
#pragma unroll
    for (int b = 0; b < BB; ++b) {
#pragma unroll
        for (int off = 32; off > 0; off >>= 1)
            acc[b] += __shfl_down(acc[b], off, 64);
    }
    if (lane == 0) {
        const float bias = bf[k * CC + o];
#pragma unroll
        for (int b = 0; b < BB; ++b)
            fil[((size_t)b * KK + k) * CC + o] = acc[b] + bias;
    }
}

// ================= k_s4: pred = fil[b] @ x, fp32 out (pipelined) ============
__global__ __launch_bounds__(256, 3) void k_s4(const float* __restrict__ x,
                                               const float* __restrict__ fil,
                                               float* __restrict__ out) {
    __shared__ short wm[20 * CC];
    __shared__ short xt[2][128 * 64];
    const int tid = threadIdx.x;
    const int b = blockIdx.x >> 7;
    const int p0 = (blockIdx.x & 127) << 7;
    const float* xb = x + ((size_t)b * CC) * HWHW + p0;
    const float* fb = fil + ((size_t)b * KK) * CC;

    for (int u = tid; u < 20 * 128; u += 256) {
        const int k = u >> 7;
        const int c4 = (u & 127) << 2;
        float4 w = {0.f, 0.f, 0.f, 0.f};
        if (k < KK) w = *(const float4*)(fb + k * CC + c4);
        s16x4 v = { (short)f2bf(w.x), (short)f2bf(w.y), (short)f2bf(w.z), (short)f2bf(w.w) };
        *(s16x4*)&wm[(k << 9) + (((c4 >> 3) ^ (k & 7)) << 3) + (c4 & 7)] = v;
    }

    const int wv = tid >> 6, ln = tid & 63;
    const int lm = ln & 15, q = ln >> 4;
    const f32x4 zz = {0.f, 0.f, 0.f, 0.f};
    f32x4 acc[2][2];
    acc[0][0] = zz; acc[0][1] = zz; acc[1][0] = zz; acc[1][1] = zz;

    const int cg0 = tid >> 5;
    const int pA  = (tid & 31) << 2;
    const float* sA = xb + (size_t)(cg0 << 2) * HWHW + pA;
    const float* sB = xb + (size_t)((cg0 + 8) << 2) * HWHW + pA;

    float4 Fa[8], Fb[8];
#pragma unroll
    for (int j = 0; j < 4; ++j) {
        Fa[j]     = *(const float4*)(sA + (size_t)j * HWHW);
        Fa[4 + j] = *(const float4*)(sB + (size_t)j * HWHW);
    }

#pragma unroll
    for (int cs = 0; cs < 8; ++cs) {
        const float4* cur = (cs & 1) ? Fb : Fa;
        float4* nxt = (cs & 1) ? Fa : Fb;
        if (cs < 7) {
            const size_t co = (size_t)((cs + 1) << 6) * HWHW;
#pragma unroll
            for (int j = 0; j < 4; ++j) {
                nxt[j]     = *(const float4*)(sA + co + (size_t)j * HWHW);
                nxt[4 + j] = *(const float4*)(sB + co + (size_t)j * HWHW);
            }
        }
        short* xts = (short*)xt[cs & 1];
#pragma unroll
        for (int h = 0; h < 2; ++h) {
            const int cg = cg0 + (h << 3);
            const float* G0 = (const float*)&cur[(h << 2) + 0];
            const float* G1 = (const float*)&cur[(h << 2) + 1];
            const float* G2 = (const float*)&cur[(h << 2) + 2];
            const float* G3 = (const float*)&cur[(h << 2) + 3];
#pragma unroll
            for (int j = 0; j < 4; ++j) {
                const int pr = pA + j;
                uint2 v = make_uint2(pk_bf16(G0[j], G1[j]), pk_bf16(G2[j], G3[j]));
                *(uint2*)&xts[(pr << 6) + (((cg >> 1) ^ (pr & 7)) << 3) + ((cg & 1) << 2)] = v;
            }
        }
        asm volatile("s_waitcnt lgkmcnt(0)" ::: "memory");
        __builtin_amdgcn_s_barrier();
        asm volatile("" ::: "memory");
#pragma unroll
        for (int ks = 0; ks < 2; ++ks) {
            const int gch = (cs << 3) + (ks << 2) + q;
            const int m1 = (lm < 3) ? (16 + lm) : 19;
            bf16x8 a0 = *(const bf16x8*)&wm[(lm << 9) + ((gch ^ (lm & 7)) << 3)];
            bf16x8 a1 = *(const bf16x8*)&wm[(m1 << 9) + ((gch ^ (m1 & 7)) << 3)];
            const int lch = (ks << 2) + q;
#pragma unroll
            for (int nt = 0; nt < 2; ++nt) {
                const int pr = (((wv << 1) + nt) << 4) + lm;
                bf16x8 bv = *(const bf16x8*)&xts[(pr << 6) + ((lch ^ (pr & 7)) << 3)];
                acc[0][nt] = __builtin_amdgcn_mfma_f32_16x16x32_bf16(a0, bv, acc[0][nt], 0, 0, 0);
                acc[1][nt] = __builtin_amdgcn_mfma_f32_16x16x32_bf16(a1, bv, acc[1][nt], 0, 0, 0);
            }
        }
    }

    float* ob = out + ((size_t)b * KK) * HWHW + p0;
#pragma unroll
    for (int mt = 0; mt < 2; ++mt)
#pragma unroll
        for (int r = 0; r < 4; ++r) {
            const int k = (mt << 4) + (q << 2) + r;
            if (k < KK) {
#pragma unroll
                for (int nt = 0; nt < 2; ++nt) {
                    const int p = (((wv << 1) + nt) << 4) + lm;
                    ob[(size_t)k * HWHW + p] = acc[mt][nt][r];
                }
            }
        }
}

extern "C" void kernel_launch(void* const* d_in, const int* in_sizes, int n_in,
                              void* d_out, int out_size, void* d_ws, size_t ws_size,
                              hipStream_t stream) {
    const float* x  = (const float*)d_in[0];
    const float* Wm = (const float*)d_in[1];
    const float* bm = (const float*)d_in[2];
    const float* Wf = (const float*)d_in[3];
    const float* bf = (const float*)d_in[4];
    float* out = (float*)d_out;

    unsigned short* mask = (unsigned short*)d_ws;                        // 4.98 MB bf16
    float* cf_part = (float*)((char*)d_ws + (size_t)BB * KK * HWHW * 2); // 4.98 MB
    float* cf  = cf_part + (size_t)16 * BB * KK * CC;                    // 311 KB
    float* fil = cf + (size_t)BB * KK * CC;                              // 311 KB

    k_s1<<<1024, 256, 0, stream>>>(x, Wm, bm, mask);
    k_s2<<<1024, 256, 0, stream>>>(x, mask, cf_part);
    k_s2r<<<(BB * KK * CC + 255) / 256, 256, 0, stream>>>(cf_part, cf);
    k_filters<<<KK * 128, 256, 0, stream>>>(Wf, bf, cf, fil);
    k_s4<<<1024, 256, 0, stream>>>(x, fil, out);
}